// Round 7
// baseline (116.081 us; speedup 1.0000x reference)
//
#include <hip/hip_runtime.h>
#include <hip/hip_bf16.h>
#include <math.h>

typedef unsigned short u16;
typedef unsigned int   u32;
typedef unsigned long long u64;

#define WS_PART  4096     // float4[8][65536]: per-cg partial angles (8 MB)

__device__ inline float bfbits2f(u32 lo16) {
    u32 u = lo16 << 16;
    return __builtin_bit_cast(float, u);
}
__device__ inline float bchi(u32 w) {   // high 16 bits as bf16 -> float
    return __builtin_bit_cast(float, w & 0xffff0000u);
}
__device__ inline float bclo(u32 w) {   // low 16 bits as bf16 -> float
    return __builtin_bit_cast(float, w << 16);
}
__device__ inline u16 f2bf(float f) {
    u32 u = __builtin_bit_cast(u32, f);
    u = u + 0x7fffu + ((u >> 16) & 1u);   // round-to-nearest-even
    return (u16)(u >> 16);
}
__device__ inline float ld_param(const void* p, int i, int isbf16) {
    return isbf16 ? bfbits2f(((const u16*)p)[i]) : ((const float*)p)[i];
}

// dtype sniff, wave-parallel (proven r4-r6): bf16-pair data has bits 14:7 of
// each u32 = a bf16 exponent, ~always in [110,130] for N(0,1); fp32 data:
// mantissa bits (~8% hit). Same classification as the original serial loop.
__device__ inline int sniff_bf16(const void* x, int t) {
    u32 xv = ((const u32*)x)[t & 63];
    u32 e  = (xv >> 7) & 0xFFu;
    u64 m  = __ballot(e >= 110u && e <= 130u);
    return (__popcll(m) >= 32) ? 1 : 0;
}

// ---------------- KA: conv partials (self-contained, zero pack VALU) -------
// grid 8192 = (b:16) x (row:64) x (cg:8); block 256 = (j:64, tc:4).
// r6 lesson: per-block weight-pack VALU loses more than the saved k0 launch.
// Fix: NO pack at all. cs is even, so channels cs,cs+1 of qubit-block q are
// 9 contiguous u32-aligned words at fc1_w_u32[q*288+(cs/2)*9] -> raw36 via
// wave-uniform s_loads (overlapped with tile staging). Each weight is used
// exactly once, extracted inline: even u16 offset = bclo (1 s_lshl), odd =
// bchi (1 s_and) -- pure SALU on SGPRs, v_fmac takes the s-operand.
__global__ __launch_bounds__(256) void kA_conv(
        const void* __restrict__ x, const void* __restrict__ fc1_w,
        float4* __restrict__ part) {
    __shared__ u32 tile[24 * 34];    // [r*8+cl][pair], 3264 B
    __shared__ float4 red4[256];     // 4 KB
    const int t = threadIdx.x;
    const int bid = blockIdx.x;
    const int cg  = bid & 7;
    const int row = (bid >> 3) & 63;
    const int b   = bid >> 9;
    const int bf = sniff_bf16(x, t);      // uniform
    const int c0 = cg * 8;
    const int tc = t >> 6;

    // ---- wave-uniform raw weight load: 36 u32 -> SGPRs --------------------
    // raw36[q*9+m] = bf16 pair (taps 2m, 2m+1) of the 18 u16 covering
    // channels cs (u16 offsets 0..8) and cs+1 (9..17) in qubit-block q.
    const int cs = __builtin_amdgcn_readfirstlane(c0 + tc * 2);
    u32 raw36[36];
    if (bf) {
        const u32* wp = (const u32*)fc1_w + (cs >> 1) * 9;   // cs even
#pragma unroll
        for (int qq = 0; qq < 4; ++qq)
#pragma unroll
            for (int m = 0; m < 9; ++m)
                raw36[qq * 9 + m] = wp[qq * 288 + m];
    } else {
        const float* wf = (const float*)fc1_w + cs * 9;
#pragma unroll
        for (int qq = 0; qq < 4; ++qq)
#pragma unroll
            for (int m = 0; m < 9; ++m) {
                u32 a  = (u32)f2bf(wf[qq * 576 + 2 * m]);      // int-only SALU
                u32 bb = (u32)f2bf(wf[qq * 576 + 2 * m + 1]);
                raw36[qq * 9 + m] = a | (bb << 16);
            }
    }

    const u32*    xu = (const u32*)x;     // bf16 pair view
    const float2* xf = (const float2*)x;  // fp32 pair view
    const int xbase = b * 131072;         // per-image pairs

    // ---- stage 24 (r,cl)-rows x 32 pairs = 768 pairs, 3 per thread --------
    {
        const int jj = t & 31;
        const int g8 = t >> 5;            // 0..7
#pragma unroll
        for (int i = 0; i < 3; ++i) {
            int rowcl = g8 + i * 8;       // 0..23 = r*8 + cl
            int r = rowcl >> 3, cl = rowcl & 7;
            int gr = row - 1 + r;
            u32 pk = 0;
            if (gr >= 0 && gr < 64) {
                int idx = xbase + (c0 + cl) * 2048 + gr * 32 + jj;
                if (bf) pk = xu[idx];
                else { float2 v = xf[idx];
                       pk = (u32)f2bf(v.x) | ((u32)f2bf(v.y) << 16); }
            }
            tile[rowcl * 34 + 1 + jj] = pk;
        }
        if (t < 48) { int rc = t >> 1; tile[rc * 34 + ((t & 1) ? 33 : 0)] = 0u; }
    }
    __syncthreads();

    // ---- conv: thread (j, tc) reduces channels tc*2, tc*2+1 ---------------
    // W(q,dj) for channel cs+cc lives at u16 offset o = cc*9 + r*3 + dj of
    // block q; all indices compile-time after unroll.
    const int j = t & 63;
    const int pj = (j + 1) >> 1;          // first u32 of the 2 needed
    const int sh = (1 - (j & 1)) * 16;    // even j: drop leading col
    float ang[4] = {0.f, 0.f, 0.f, 0.f};
#pragma unroll
    for (int cc = 0; cc < 2; ++cc) {
#pragma unroll
        for (int r = 0; r < 3; ++r) {
            const int cl = tc * 2 + cc;
            const u32* rp = tile + (r * 8 + cl) * 34 + pj;
            u32 lo = rp[0], hi = rp[1];           // ds_read2_b32
            u64 v = (((u64)hi << 32) | lo) >> sh;
            u32 vlo = (u32)v, vhi = (u32)(v >> 32);
            float e0 = bclo(vlo);                 // col j-1
            float e1 = bchi(vlo);                 // col j
            float e2 = bclo(vhi);                 // col j+1
            const int o0 = cc * 9 + r * 3;        // u16 offset of dj=0
#pragma unroll
            for (int q = 0; q < 4; ++q) {
                const u32* rq = raw36 + q * 9;
                float w0 = ((o0    ) & 1) ? bchi(rq[(o0    ) >> 1]) : bclo(rq[(o0    ) >> 1]);
                float w1 = ((o0 + 1) & 1) ? bchi(rq[(o0 + 1) >> 1]) : bclo(rq[(o0 + 1) >> 1]);
                float w2 = ((o0 + 2) & 1) ? bchi(rq[(o0 + 2) >> 1]) : bclo(rq[(o0 + 2) >> 1]);
                ang[q] += e0 * w0 + e1 * w1 + e2 * w2;
            }
        }
    }

    red4[tc * 64 + j] = make_float4(ang[0], ang[1], ang[2], ang[3]);
    __syncthreads();
    if (t < 64) {
        float4 a0 = red4[t], a1 = red4[64 + t], a2 = red4[128 + t], a3 = red4[192 + t];
        float4 s = make_float4(a0.x + a1.x + a2.x + a3.x,
                               a0.y + a1.y + a2.y + a3.y,
                               a0.z + a1.z + a2.z + a3.z,
                               a0.w + a1.w + a2.w + a3.w);
        // [cg][pixel] layout: lane-consecutive 16B stores (coalesced)
        part[cg * 65536 + b * 4096 + row * 64 + t] = s;
    }
}

// ---------------- KB: reduce partials + circuit + output FC ----------------
// grid 256; block 256; one pixel per thread (r5). Self-contained (r4/r6
// proven): sniffs dtype, t<8 builds gate matrices into LDS while every
// thread's 8 partial-loads are in flight; epilogue unpacks fc_w/fc_b from
// global (L2-resident).
__global__ __launch_bounds__(256) void kB_circuit_fc(
        const void* __restrict__ x,
        const void* __restrict__ fc1_b, const void* __restrict__ u3p,
        const void* __restrict__ cu3p,  const void* __restrict__ fc_w,
        const void* __restrict__ fc_b,  const float4* __restrict__ part,
        void* __restrict__ out) {
    __shared__ float smG[64];        // 8 gates x (2x2 complex)
    __shared__ float4 smEz[256];
    const int t = threadIdx.x;
    const int bp = blockIdx.x * 256 + t;        // global pixel
    const int bf = sniff_bf16(x, t);            // uniform

    // ---- per-thread: sum 8 partials (loads issue before the barrier) ------
    float ax = 0.f, ay = 0.f, az = 0.f, aw = 0.f;
#pragma unroll
    for (int g = 0; g < 8; ++g) {
        float4 a = part[g * 65536 + bp];
        ax += a.x; ay += a.y; az += a.z; aw += a.w;
    }
    // ---- t<8: gate matrices (overlaps partial-load latency) ---------------
    if (t < 8) {
        int w = t & 3;
        const void* p = (t < 4) ? u3p : cu3p;
        float th = ld_param(p, w * 3 + 0, bf);
        float ph = ld_param(p, w * 3 + 1, bf);
        float la = ld_param(p, w * 3 + 2, bf);
        float c = cosf(0.5f * th), s = sinf(0.5f * th);
        float cl = cosf(la), sl = sinf(la);
        float cp = cosf(ph), sp = sinf(ph);
        float cpl = cp * cl - sp * sl, spl = sp * cl + cp * sl;
        float* m = smG + t * 8;
        // U3 = [[cosT, -e^{i la} sinT], [e^{i ph} sinT, e^{i(ph+la)} cosT]]
        m[0] = c;        m[1] = 0.f;
        m[2] = -cl * s;  m[3] = -sl * s;
        m[4] = cp * s;   m[5] = sp * s;
        m[6] = cpl * c;  m[7] = spl * c;
    }
    __syncthreads();

    float angf[4];
    angf[0] = ld_param(fc1_b, 0, bf) + ax;
    angf[1] = ld_param(fc1_b, 1, bf) + ay;
    angf[2] = ld_param(fc1_b, 2, bf) + az;
    angf[3] = ld_param(fc1_b, 3, bf) + aw;

    // ---- quantum circuit: product state after RY+U3, CU3 ring, <Z> --------
    {
        const float* G = smG;
        float vr[4][2], vi[4][2];
#pragma unroll
        for (int w = 0; w < 4; ++w) {
            float sa, ca;
            __sincosf(0.5f * angf[w], &sa, &ca);   // RY|0> = (cos, sin)
            const float* m = G + w * 8;
            vr[w][0] = m[0] * ca + m[2] * sa;  vi[w][0] = m[1] * ca + m[3] * sa;
            vr[w][1] = m[4] * ca + m[6] * sa;  vi[w][1] = m[5] * ca + m[7] * sa;
        }
        float t01r[4], t01i[4], t23r[4], t23i[4];
#pragma unroll
        for (int a = 0; a < 2; ++a)
#pragma unroll
            for (int bq = 0; bq < 2; ++bq) {
                t01r[a * 2 + bq] = vr[0][a] * vr[1][bq] - vi[0][a] * vi[1][bq];
                t01i[a * 2 + bq] = vr[0][a] * vi[1][bq] + vi[0][a] * vr[1][bq];
                t23r[a * 2 + bq] = vr[2][a] * vr[3][bq] - vi[2][a] * vi[3][bq];
                t23i[a * 2 + bq] = vr[2][a] * vi[3][bq] + vi[2][a] * vr[3][bq];
            }
        float ar[16], ai[16];   // amp index n = q0*8 + q1*4 + q2*2 + q3
#pragma unroll
        for (int n = 0; n < 16; ++n) {
            int hi = n >> 2, lo = n & 3;
            ar[n] = t01r[hi] * t23r[lo] - t01i[hi] * t23i[lo];
            ai[n] = t01r[hi] * t23i[lo] + t01i[hi] * t23r[lo];
        }
        // CU3 ring: control w, target (w+1)%4; U on control==1 subspace
#pragma unroll
        for (int w = 0; w < 4; ++w) {
            const float* m = G + 32 + w * 8;
            const int cb = 8 >> w;
            const int tb = 8 >> ((w + 1) & 3);
#pragma unroll
            for (int n = 0; n < 16; ++n) {
                if ((n & cb) != 0 && (n & tb) == 0) {
                    int n1 = n | tb;
                    float a0r = ar[n], a0i = ai[n], a1r = ar[n1], a1i = ai[n1];
                    ar[n]  = m[0] * a0r - m[1] * a0i + m[2] * a1r - m[3] * a1i;
                    ai[n]  = m[0] * a0i + m[1] * a0r + m[2] * a1i + m[3] * a1r;
                    ar[n1] = m[4] * a0r - m[5] * a0i + m[6] * a1r - m[7] * a1i;
                    ai[n1] = m[4] * a0i + m[5] * a0r + m[6] * a1i + m[7] * a1r;
                }
            }
        }
        float ez[4] = {0.f, 0.f, 0.f, 0.f};
#pragma unroll
        for (int n = 0; n < 16; ++n) {
            float pr = ar[n] * ar[n] + ai[n] * ai[n];
#pragma unroll
            for (int w = 0; w < 4; ++w)
                ez[w] += ((n >> (3 - w)) & 1) ? -pr : pr;
        }
        smEz[t] = make_float4(ez[0], ez[1], ez[2], ez[3]);
    }
    __syncthreads();

    // ---- epilogue: thread owns oc group og..og+7; pixel varies over ch ----
    // consecutive lanes -> consecutive uint4 (1 KB/instruction).
    const int og = (t & 15) * 8;
    float4 w0, w1, w2, w3, w4, w5, w6, w7, bA, bB;
    if (bf) {
        const uint4* fw4 = (const uint4*)fc_w + (og >> 1);  // 2 oc rows/uint4
        uint4 qa = fw4[0], qb = fw4[1], qc = fw4[2], qd = fw4[3];
        w0 = make_float4(bclo(qa.x), bchi(qa.x), bclo(qa.y), bchi(qa.y));
        w1 = make_float4(bclo(qa.z), bchi(qa.z), bclo(qa.w), bchi(qa.w));
        w2 = make_float4(bclo(qb.x), bchi(qb.x), bclo(qb.y), bchi(qb.y));
        w3 = make_float4(bclo(qb.z), bchi(qb.z), bclo(qb.w), bchi(qb.w));
        w4 = make_float4(bclo(qc.x), bchi(qc.x), bclo(qc.y), bchi(qc.y));
        w5 = make_float4(bclo(qc.z), bchi(qc.z), bclo(qc.w), bchi(qc.w));
        w6 = make_float4(bclo(qd.x), bchi(qd.x), bclo(qd.y), bchi(qd.y));
        w7 = make_float4(bclo(qd.z), bchi(qd.z), bclo(qd.w), bchi(qd.w));
        uint4 qbb = ((const uint4*)fc_b)[og >> 3];
        bA = make_float4(bclo(qbb.x), bchi(qbb.x), bclo(qbb.y), bchi(qbb.y));
        bB = make_float4(bclo(qbb.z), bchi(qbb.z), bclo(qbb.w), bchi(qbb.w));
    } else {
        const float4* fw4 = (const float4*)fc_w + og;       // 1 oc row/float4
        w0 = fw4[0]; w1 = fw4[1]; w2 = fw4[2]; w3 = fw4[3];
        w4 = fw4[4]; w5 = fw4[5]; w6 = fw4[6]; w7 = fw4[7];
        bA = ((const float4*)fc_b)[(og >> 2)];
        bB = ((const float4*)fc_b)[(og >> 2) + 1];
    }
#pragma unroll
    for (int ch = 0; ch < 16; ++ch) {
        const int pl = (t >> 4) + ch * 16;   // pixel within block (0..255)
        const float4 ez = smEz[pl];
        float v0 = bA.x + ez.x*w0.x + ez.y*w0.y + ez.z*w0.z + ez.w*w0.w;
        float v1 = bA.y + ez.x*w1.x + ez.y*w1.y + ez.z*w1.z + ez.w*w1.w;
        float v2 = bA.z + ez.x*w2.x + ez.y*w2.y + ez.z*w2.z + ez.w*w2.w;
        float v3 = bA.w + ez.x*w3.x + ez.y*w3.y + ez.z*w3.z + ez.w*w3.w;
        float v4 = bB.x + ez.x*w4.x + ez.y*w4.y + ez.z*w4.z + ez.w*w4.w;
        float v5 = bB.y + ez.x*w5.x + ez.y*w5.y + ez.z*w5.z + ez.w*w5.w;
        float v6 = bB.z + ez.x*w6.x + ez.y*w6.y + ez.z*w6.z + ez.w*w6.w;
        float v7 = bB.w + ez.x*w7.x + ez.y*w7.y + ez.z*w7.z + ez.w*w7.w;
        if (bf) {
            u32 p0 = (u32)f2bf(v0) | ((u32)f2bf(v1) << 16);
            u32 p1 = (u32)f2bf(v2) | ((u32)f2bf(v3) << 16);
            u32 p2 = (u32)f2bf(v4) | ((u32)f2bf(v5) << 16);
            u32 p3 = (u32)f2bf(v6) | ((u32)f2bf(v7) << 16);
            ((uint4*)out)[blockIdx.x * 4096 + ch * 256 + t] =
                make_uint4(p0, p1, p2, p3);
        } else {
            float4* o = (float4*)out + (blockIdx.x * 8192 + ch * 512 + 2 * t);
            o[0] = make_float4(v0, v1, v2, v3);
            o[1] = make_float4(v4, v5, v6, v7);
        }
    }
}

extern "C" void kernel_launch(void* const* d_in, const int* in_sizes, int n_in,
                              void* d_out, int out_size, void* d_ws, size_t ws_size,
                              hipStream_t stream) {
    (void)in_sizes; (void)n_in; (void)out_size; (void)ws_size;
    float* ws = (float*)d_ws;
    float4* part = (float4*)(ws + WS_PART);
    kA_conv<<<dim3(8192), dim3(256), 0, stream>>>(d_in[0], d_in[1], part);
    kB_circuit_fc<<<dim3(256), dim3(256), 0, stream>>>(
        d_in[0], d_in[2], d_in[3], d_in[4], d_in[5], d_in[6], part, d_out);
}

// Round 8
// 109.049 us; speedup vs baseline: 1.0645x; 1.0645x over previous
//
#include <hip/hip_runtime.h>
#include <hip/hip_bf16.h>
#include <math.h>

typedef unsigned short u16;
typedef unsigned int   u32;
typedef unsigned long long u64;

// ws layout (float offsets)
#define WS_W2    0        // 1152 u32: packed bf16 conv weights [c][r][6]
#define WS_B4    2304     // 4:    fc1_b fp32
#define WS_FCW   2308     // 512:  fc_w [oc][q] fp32   (16B aligned)
#define WS_FCB   2820     // 128:  fc_b fp32           (16B aligned)
#define WS_GATES 2948     // 64:   8 gates x (2x2 complex) = 8 floats each
#define WS_FLAG  3012     // 1:    1.0 = inputs are bf16, 0.0 = fp32
#define WS_PART  4096     // float4[8][65536]: per-cg partial angles (8 MB)

__device__ inline float bfbits2f(u32 lo16) {
    u32 u = lo16 << 16;
    return __builtin_bit_cast(float, u);
}
__device__ inline float bchi(u32 w) {   // high 16 bits as bf16 -> float
    return __builtin_bit_cast(float, w & 0xffff0000u);
}
__device__ inline float bclo(u32 w) {   // low 16 bits as bf16 -> float
    return __builtin_bit_cast(float, w << 16);
}
__device__ inline u16 f2bf(float f) {
    u32 u = __builtin_bit_cast(u32, f);
    u = u + 0x7fffu + ((u >> 16) & 1u);   // round-to-nearest-even
    return (u16)(u >> 16);
}
__device__ inline float ld_param(const void* p, int i, int isbf16) {
    return isbf16 ? bfbits2f(((const u16*)p)[i]) : ((const float*)p)[i];
}

// ---------------- K0: sniff dtype, pack weights, build gate matrices -------
__global__ __launch_bounds__(256) void k0_prep(
        const void* __restrict__ x,
        const void* __restrict__ fc1_w, const void* __restrict__ fc1_b,
        const void* __restrict__ u3p,   const void* __restrict__ cu3p,
        const void* __restrict__ fc_w,  const void* __restrict__ fc_b,
        float* __restrict__ ws) {
    __shared__ int sflag;
    int t = threadIdx.x;
    if (t == 0) {
        // bf16-pair data: bits 14:7 of each u32 are a bf16 exponent, ~always
        // in [110,130] for N(0,1). fp32 data: those are mantissa bits (~8%).
        const u32* xw = (const u32*)x;
        int cnt = 0;
        for (int i = 0; i < 64; ++i) {
            u32 e = (xw[i] >> 7) & 0xFFu;
            if (e >= 110 && e <= 130) ++cnt;
        }
        sflag = (cnt >= 32) ? 1 : 0;
        ws[WS_FLAG] = (float)sflag;
    }
    __syncthreads();
    const int bf = sflag;
    // packed conv weights: u32[c][r][6]; u32 p packs (q,dj) pairs q-major:
    // idx = q*3+dj; lo16 = bf16(w[idx=2p]), hi16 = bf16(w[idx=2p+1])
    u32* wpk = (u32*)ws + WS_W2;
    for (int idx = t; idx < 1152; idx += 256) {
        int c = idx / 18;
        int rem = idx - c * 18;
        int r = rem / 6;
        int p = rem - r * 6;
        int i0 = 2 * p, i1 = 2 * p + 1;
        int q0 = i0 / 3, d0 = i0 - 3 * q0;
        int q1 = i1 / 3, d1 = i1 - 3 * q1;
        u32 lo = f2bf(ld_param(fc1_w, q0 * 576 + c * 9 + r * 3 + d0, bf));
        u32 hi = f2bf(ld_param(fc1_w, q1 * 576 + c * 9 + r * 3 + d1, bf));
        wpk[idx] = lo | (hi << 16);
    }
    if (t < 4)   ws[WS_B4 + t] = ld_param(fc1_b, t, bf);
    for (int idx = t; idx < 512; idx += 256) ws[WS_FCW + idx] = ld_param(fc_w, idx, bf);
    if (t < 128) ws[WS_FCB + t] = ld_param(fc_b, t, bf);
    if (t < 8) {
        int w = t & 3;
        const void* p = (t < 4) ? u3p : cu3p;
        float th = ld_param(p, w * 3 + 0, bf);
        float ph = ld_param(p, w * 3 + 1, bf);
        float la = ld_param(p, w * 3 + 2, bf);
        float c = cosf(0.5f * th), s = sinf(0.5f * th);
        float cl = cosf(la), sl = sinf(la);
        float cp = cosf(ph), sp = sinf(ph);
        float cpl = cp * cl - sp * sl, spl = sp * cl + cp * sl;
        float* m = ws + WS_GATES + t * 8;
        // U3 = [[cosT, -e^{i la} sinT], [e^{i ph} sinT, e^{i(ph+la)} cosT]]
        m[0] = c;        m[1] = 0.f;
        m[2] = -cl * s;  m[3] = -sl * s;
        m[4] = cp * s;   m[5] = sp * s;
        m[6] = cpl * c;  m[7] = spl * c;
    }
}

// ---------------- KA: conv partials -----------------------------------------
// grid 8192 = (b:16) x (row:64) x (cg:8); block 256 = (j:64, tc:4).
// Wave's 2 channels' packed weights bulk-s_loaded into SGPRs BEFORE the
// barrier (no SMEM in the conv loop -> no lgkmcnt(0) drains of ds_reads).
// 8 blocks/CU -> 32 waves/CU.
__global__ __launch_bounds__(256) void kA_conv(
        const void* __restrict__ x, const float* __restrict__ ws,
        float4* __restrict__ part) {
    __shared__ u32 tile[24 * 34];    // [r*8+cl][pair], 3264 B
    __shared__ float4 red4[256];     // 4 KB
    const int t = threadIdx.x;
    const int bid = blockIdx.x;
    const int cg  = bid & 7;
    const int row = (bid >> 3) & 63;
    const int b   = bid >> 9;
    const int bf = (ws[WS_FLAG] != 0.0f) ? 1 : 0;   // uniform
    const int c0 = cg * 8;
    const int tc = t >> 6;

    // ---- hoisted wave-uniform weight load: 36 u32 -> SGPRs (s_load) -------
    const int cs = __builtin_amdgcn_readfirstlane(c0 + tc * 2);
    const u32* wpk = (const u32*)ws + WS_W2 + cs * 18;
    u32 w36[36];
#pragma unroll
    for (int i = 0; i < 36; ++i) w36[i] = wpk[i];

    const u32*    xu = (const u32*)x;     // bf16 pair view
    const float2* xf = (const float2*)x;  // fp32 pair view
    const int xbase = b * 131072;         // per-image pairs

    // ---- stage 24 (r,cl)-rows x 32 pairs = 768 pairs, 3 per thread --------
    {
        const int jj = t & 31;
        const int g8 = t >> 5;            // 0..7
#pragma unroll
        for (int i = 0; i < 3; ++i) {
            int rowcl = g8 + i * 8;       // 0..23 = r*8 + cl
            int r = rowcl >> 3, cl = rowcl & 7;
            int gr = row - 1 + r;
            u32 pk = 0;
            if (gr >= 0 && gr < 64) {
                int idx = xbase + (c0 + cl) * 2048 + gr * 32 + jj;
                if (bf) pk = xu[idx];
                else { float2 v = xf[idx];
                       pk = (u32)f2bf(v.x) | ((u32)f2bf(v.y) << 16); }
            }
            tile[rowcl * 34 + 1 + jj] = pk;
        }
        if (t < 48) { int rc = t >> 1; tile[rc * 34 + ((t & 1) ? 33 : 0)] = 0u; }
    }
    __syncthreads();

    // ---- conv: thread (j, tc) reduces channels tc*2, tc*2+1 ---------------
    const int j = t & 63;
    const int pj = (j + 1) >> 1;          // first u32 of the 2 needed
    const int sh = (1 - (j & 1)) * 16;    // even j: drop leading col
    float ang0 = 0.f, ang1 = 0.f, ang2 = 0.f, ang3 = 0.f;
#pragma unroll
    for (int cc = 0; cc < 2; ++cc) {
        const int cl = tc * 2 + cc;
#pragma unroll
        for (int r = 0; r < 3; ++r) {
            const u32* rp = tile + (r * 8 + cl) * 34 + pj;
            u32 lo = rp[0], hi = rp[1];           // ds_read2_b32
            u64 v = (((u64)hi << 32) | lo) >> sh;
            u32 vlo = (u32)v, vhi = (u32)(v >> 32);
            float e0 = bclo(vlo);                 // col j-1
            float e1 = bchi(vlo);                 // col j
            float e2 = bclo(vhi);                 // col j+1
            const int wb = cc * 18 + r * 6;
            u32 u0 = w36[wb], u1 = w36[wb + 1], u2 = w36[wb + 2];
            u32 u3 = w36[wb + 3], u4 = w36[wb + 4], u5 = w36[wb + 5];
            // SALU unpack (s_lshl/s_and); v_fmac takes SGPR operand
            ang0 += e0 * bclo(u0) + e1 * bchi(u0) + e2 * bclo(u1);
            ang1 += e0 * bchi(u1) + e1 * bclo(u2) + e2 * bchi(u2);
            ang2 += e0 * bclo(u3) + e1 * bchi(u3) + e2 * bclo(u4);
            ang3 += e0 * bchi(u4) + e1 * bclo(u5) + e2 * bchi(u5);
        }
    }

    red4[tc * 64 + j] = make_float4(ang0, ang1, ang2, ang3);
    __syncthreads();
    if (t < 64) {
        float4 a0 = red4[t], a1 = red4[64 + t], a2 = red4[128 + t], a3 = red4[192 + t];
        float4 s = make_float4(a0.x + a1.x + a2.x + a3.x,
                               a0.y + a1.y + a2.y + a3.y,
                               a0.z + a1.z + a2.z + a3.z,
                               a0.w + a1.w + a2.w + a3.w);
        // [cg][pixel] layout: lane-consecutive 16B stores (coalesced)
        part[cg * 65536 + b * 4096 + row * 64 + t] = s;
    }
}

// ---------------- KB: reduce partials + circuit + output FC ----------------
// grid 256; block 256; one pixel per thread. Each thread sums its pixel's 8
// partials (coalesced float4), runs the 4-qubit circuit in-register, writes
// smEz, one barrier, then the transposed coalesced FC epilogue.
__global__ __launch_bounds__(256) void kB_circuit_fc(
        const float* __restrict__ ws, const float4* __restrict__ part,
        void* __restrict__ out) {
    __shared__ float4 smEz[256];
    const int t = threadIdx.x;
    const int bp = blockIdx.x * 256 + t;        // global pixel
    const int bf = (ws[WS_FLAG] != 0.0f) ? 1 : 0;

    // ---- per-thread: sum 8 partials + bias ---------------------------------
    float ax = 0.f, ay = 0.f, az = 0.f, aw = 0.f;
#pragma unroll
    for (int g = 0; g < 8; ++g) {
        float4 a = part[g * 65536 + bp];
        ax += a.x; ay += a.y; az += a.z; aw += a.w;
    }
    float angf[4];
    angf[0] = ws[WS_B4 + 0] + ax;
    angf[1] = ws[WS_B4 + 1] + ay;
    angf[2] = ws[WS_B4 + 2] + az;
    angf[3] = ws[WS_B4 + 3] + aw;

    // ---- quantum circuit: product state after RY+U3, CU3 ring, <Z> --------
    const float* G = ws + WS_GATES;             // uniform scalar loads
    {
        float vr[4][2], vi[4][2];
#pragma unroll
        for (int w = 0; w < 4; ++w) {
            float sa, ca;
            __sincosf(0.5f * angf[w], &sa, &ca);   // RY|0> = (cos, sin)
            const float* m = G + w * 8;
            vr[w][0] = m[0] * ca + m[2] * sa;  vi[w][0] = m[1] * ca + m[3] * sa;
            vr[w][1] = m[4] * ca + m[6] * sa;  vi[w][1] = m[5] * ca + m[7] * sa;
        }
        float t01r[4], t01i[4], t23r[4], t23i[4];
#pragma unroll
        for (int a = 0; a < 2; ++a)
#pragma unroll
            for (int bq = 0; bq < 2; ++bq) {
                t01r[a * 2 + bq] = vr[0][a] * vr[1][bq] - vi[0][a] * vi[1][bq];
                t01i[a * 2 + bq] = vr[0][a] * vi[1][bq] + vi[0][a] * vr[1][bq];
                t23r[a * 2 + bq] = vr[2][a] * vr[3][bq] - vi[2][a] * vi[3][bq];
                t23i[a * 2 + bq] = vr[2][a] * vi[3][bq] + vi[2][a] * vr[3][bq];
            }
        float ar[16], ai[16];   // amp index n = q0*8 + q1*4 + q2*2 + q3
#pragma unroll
        for (int n = 0; n < 16; ++n) {
            int hi = n >> 2, lo = n & 3;
            ar[n] = t01r[hi] * t23r[lo] - t01i[hi] * t23i[lo];
            ai[n] = t01r[hi] * t23i[lo] + t01i[hi] * t23r[lo];
        }
        // CU3 ring: control w, target (w+1)%4; U on control==1 subspace
#pragma unroll
        for (int w = 0; w < 4; ++w) {
            const float* m = G + 32 + w * 8;
            const int cb = 8 >> w;
            const int tb = 8 >> ((w + 1) & 3);
#pragma unroll
            for (int n = 0; n < 16; ++n) {
                if ((n & cb) != 0 && (n & tb) == 0) {
                    int n1 = n | tb;
                    float a0r = ar[n], a0i = ai[n], a1r = ar[n1], a1i = ai[n1];
                    ar[n]  = m[0] * a0r - m[1] * a0i + m[2] * a1r - m[3] * a1i;
                    ai[n]  = m[0] * a0i + m[1] * a0r + m[2] * a1i + m[3] * a1r;
                    ar[n1] = m[4] * a0r - m[5] * a0i + m[6] * a1r - m[7] * a1i;
                    ai[n1] = m[4] * a0i + m[5] * a0r + m[6] * a1i + m[7] * a1r;
                }
            }
        }
        float ez[4] = {0.f, 0.f, 0.f, 0.f};
#pragma unroll
        for (int n = 0; n < 16; ++n) {
            float pr = ar[n] * ar[n] + ai[n] * ai[n];
#pragma unroll
            for (int w = 0; w < 4; ++w)
                ez[w] += ((n >> (3 - w)) & 1) ? -pr : pr;
        }
        smEz[t] = make_float4(ez[0], ez[1], ez[2], ez[3]);
    }
    __syncthreads();

    // ---- epilogue: thread owns oc group og..og+7; pixel varies over ch ----
    // consecutive lanes -> consecutive uint4 (1 KB/instruction).
    const int og = (t & 15) * 8;
    const float4* fw4 = (const float4*)(ws + WS_FCW) + og;  // 8 float4
    const float*  fbp = ws + WS_FCB + og;
    float4 w0 = fw4[0], w1 = fw4[1], w2 = fw4[2], w3 = fw4[3];
    float4 w4 = fw4[4], w5 = fw4[5], w6 = fw4[6], w7 = fw4[7];
    float4 bA = *(const float4*)fbp, bB = *(const float4*)(fbp + 4);
#pragma unroll
    for (int ch = 0; ch < 16; ++ch) {
        const int pl = (t >> 4) + ch * 16;   // pixel within block (0..255)
        const float4 ez = smEz[pl];
        float v0 = bA.x + ez.x*w0.x + ez.y*w0.y + ez.z*w0.z + ez.w*w0.w;
        float v1 = bA.y + ez.x*w1.x + ez.y*w1.y + ez.z*w1.z + ez.w*w1.w;
        float v2 = bA.z + ez.x*w2.x + ez.y*w2.y + ez.z*w2.z + ez.w*w2.w;
        float v3 = bA.w + ez.x*w3.x + ez.y*w3.y + ez.z*w3.z + ez.w*w3.w;
        float v4 = bB.x + ez.x*w4.x + ez.y*w4.y + ez.z*w4.z + ez.w*w4.w;
        float v5 = bB.y + ez.x*w5.x + ez.y*w5.y + ez.z*w5.z + ez.w*w5.w;
        float v6 = bB.z + ez.x*w6.x + ez.y*w6.y + ez.z*w6.z + ez.w*w6.w;
        float v7 = bB.w + ez.x*w7.x + ez.y*w7.y + ez.z*w7.z + ez.w*w7.w;
        if (bf) {
            u32 p0 = (u32)f2bf(v0) | ((u32)f2bf(v1) << 16);
            u32 p1 = (u32)f2bf(v2) | ((u32)f2bf(v3) << 16);
            u32 p2 = (u32)f2bf(v4) | ((u32)f2bf(v5) << 16);
            u32 p3 = (u32)f2bf(v6) | ((u32)f2bf(v7) << 16);
            ((uint4*)out)[blockIdx.x * 4096 + ch * 256 + t] =
                make_uint4(p0, p1, p2, p3);
        } else {
            float4* o = (float4*)out + (blockIdx.x * 8192 + ch * 512 + 2 * t);
            o[0] = make_float4(v0, v1, v2, v3);
            o[1] = make_float4(v4, v5, v6, v7);
        }
    }
}

extern "C" void kernel_launch(void* const* d_in, const int* in_sizes, int n_in,
                              void* d_out, int out_size, void* d_ws, size_t ws_size,
                              hipStream_t stream) {
    float* ws = (float*)d_ws;
    float4* part = (float4*)(ws + WS_PART);
    k0_prep<<<dim3(1), dim3(256), 0, stream>>>(d_in[0], d_in[1], d_in[2], d_in[3],
                                               d_in[4], d_in[5], d_in[6], ws);
    kA_conv<<<dim3(8192), dim3(256), 0, stream>>>(d_in[0], ws, part);
    kB_circuit_fc<<<dim3(256), dim3(256), 0, stream>>>(ws, part, d_out);
}